// Round 6
// baseline (228.586 us; speedup 1.0000x reference)
//
#include <hip/hip_runtime.h>
#include <hip/hip_bf16.h>

// ---------------- problem constants ----------------
#define HW    4096      // H*W
#define BB    8         // batch
#define TT    8         // time steps

// gate pre-scales folded into w_hh / w_x / bias at stage time:
//   i,f,o rows: * -log2(e)   -> sigmoid(x) = rcp(exp2(acc)+1)
//   g rows:     * 2*log2(e)  -> tanh(x) = (exp2(acc)-1)/(exp2(acc)+1)
constexpr float SI = -1.44269504088896340736f; // -log2(e)
constexpr float SG =  2.88539008177792681472f; // 2*log2(e)

typedef _Float16 halfx8 __attribute__((ext_vector_type(8)));
typedef _Float16 halfx4 __attribute__((ext_vector_type(4)));
typedef float    floatx4 __attribute__((ext_vector_type(4)));
typedef float    floatx2 __attribute__((ext_vector_type(2)));

__device__ inline float fast_exp2(float x) {
#if __has_builtin(__builtin_amdgcn_exp2f)
    return __builtin_amdgcn_exp2f(x);
#else
    return __builtin_exp2f(x);
#endif
}
__device__ inline float fast_rcp(float x) {
#if __has_builtin(__builtin_amdgcn_rcpf)
    return __builtin_amdgcn_rcpf(x);
#else
    return 1.0f / x;
#endif
}
__device__ inline floatx2 exp2x2(floatx2 x) {
    floatx2 r; r.x = fast_exp2(x.x); r.y = fast_exp2(x.y); return r;
}
__device__ inline floatx2 rcpx2(floatx2 x) {
    floatx2 r; r.x = fast_rcp(x.x); r.y = fast_rcp(x.y); return r;
}

union pack8 { _Float16 h[8]; uint4 u; };

// ---------------- fully fused conv_in + LSTM + conv_out, SINGLE LAUNCH ----
// Block = 512 threads = 8 waves = ONE 16-pixel tile x ALL 8 groups.
// r9:  common-denominator LSTM cell; 5 exp2 + 2 rcp /elem (weights pre-scaled).
// r11: gate-column PERMUTATION — frag column sc of block nb=(hb+4gi) holds
//      orig gate row 64*gi+4*sc+hb, so thread (s,hb) produces hid=4s+hb and
//      writes h as ONE ds_write_b64 per row.
// r12/r13: occupancy cliff for this 8-wave block is between reported-VGPR
//      64 (2 blocks/CU, occ ~42%) and 108 (1 block/CU, occ 22%) — unified
//      VGPR+AGPR budget ~128/wave at 4 waves/SIMD, with ~40 hidden AGPRs.
//      => keep reported VGPR <= 64; weight frags/wxb STAY in LDS per-t
//      (asm clobber enforces), only transient regs allowed.
// r14: prep_kernel ELIMINATED (the prep dispatch + launch gap was a stable
//      ~46 us of the 223 us bench, vs 177 us lstm dispatch). Each block now
//      repacks w_hh -> f16 B-frags and {w_x,bias} directly during staging:
//      expression-identical arithmetic to the old prep (same cvt path) ->
//      bit-identical results. w_hh (64 KB) is L2-resident; FETCH unchanged.
//      Staging loop unroll-capped (2) so transient loads can't cross the
//      register cliff.
// LDS = 79872 B <= 81920 -> 2 blocks/CU = 16 waves/CU.
__global__ __launch_bounds__(512) void lstm_kernel(
    const float* __restrict__ hin,    // (B, 64, HW) original input h
    float* __restrict__ out,          // (B, 64, HW) final output
    const float* __restrict__ w_in,   // (64, 64)
    const float* __restrict__ b_in,   // (64,)
    const float* __restrict__ w_ih,   // (256, 1)
    const float* __restrict__ w_hh,   // (256, 64)
    const float* __restrict__ b_ih,   // (256,)
    const float* __restrict__ b_hh,   // (256,)
    const float* __restrict__ w_s,    // (1, 64)
    const float* __restrict__ b_s_p,  // (1,)
    const float* __restrict__ b_out,  // (64,)
    const float* __restrict__ w_out) {// (64, 64) [o][c]
    __shared__ uint4 wfrag_lds[2176];                  // 34816 B
    __shared__ floatx2 wxb_lds[256];                   // 2048 B
    __shared__ __align__(16) float x_lds[1024];        // 4096 B: [g][t][px16]
    __shared__ __align__(16) _Float16 h_lds[9216];     // 18432 B: 8 waves x 16 x 72
    __shared__ __align__(16) float stile[1024];        // 4096 B: [c64][px16]; aliases hin staging
    __shared__ __align__(16) float wt_lds[4096];       // 16384 B: w_in, then w_out

    int tid = threadIdx.x;
    int ptile = blockIdx.x & 255;         // 256 tiles of 16 px
    int b     = blockIdx.x >> 8;
    int p0 = ptile * 16;

    int lane = tid & 63;
    int wv   = tid >> 6;                  // 0..7 == group g
    int g    = wv;
    int s    = lane & 15;                 // seq-local == pixel-local
    int q    = lane >> 4;

    // ---- stage + repack w_hh -> B-fragment-ordered f16 (pre-scaled).
    // frag fi = nb*2+kc; entry e = fi*64 + l. lane l holds
    // B[k=kc*32+(l>>4)*8+j][n=(l&15)] = w_hh[gate][hid]*sc with the r11
    // permuted gate = 64*gi + 4*(l&15) + hb  (nb = hb+4*gi).
    #pragma unroll 2
    for (int i = 0; i < 4; ++i) {
        int e = tid + 512 * i;
        int l  = e & 63;
        int fi = e >> 6;
        int nb = fi >> 1, kc = fi & 1;
        int hb = nb & 3, gi = nb >> 2;
        int gate = gi * 64 + 4 * (l & 15) + hb;
        int hid  = kc * 32 + (l >> 4) * 8;
        float sc = (gi == 2) ? SG : SI;
        const float* src = w_hh + gate * 64 + hid;     // 32B-aligned
        floatx4 s0 = *(const floatx4*)(src);
        floatx4 s1 = *(const floatx4*)(src + 4);
        pack8 p;
        #pragma unroll
        for (int j = 0; j < 4; ++j) {
            p.h[j]     = (_Float16)(s0[j] * sc);
            p.h[4 + j] = (_Float16)(s1[j] * sc);
        }
        wfrag_lds[e] = p.u;
    }
    // s-projection fragments (frags 32,33): B[k][0]=w_s[k] (UNSCALED)
    if (tid < 128) {
        int l = tid & 63, kc = tid >> 6;
        pack8 p;
        #pragma unroll
        for (int j = 0; j < 8; ++j) p.h[j] = (_Float16)0.0f;
        if ((l & 15) == 0) {
            #pragma unroll
            for (int j = 0; j < 8; ++j)
                p.h[j] = (_Float16)w_s[kc * 32 + (l >> 4) * 8 + j];
        }
        wfrag_lds[2048 + tid] = p.u;
    }
    // {w_x, bias} pairs, permuted + pre-scaled.
    // read idx = s + 16*hb + 64*gi  ->  gate 64*gi + 4*s + hb
    if (tid < 256) {
        int s_ = tid & 15, hb2 = (tid >> 4) & 3, gi = tid >> 6;
        int gate = gi * 64 + 4 * s_ + hb2;
        float sc = (gi == 2) ? SG : SI;
        floatx2 v; v.x = w_ih[gate] * sc; v.y = (b_ih[gate] + b_hh[gate]) * sc;
        wxb_lds[tid] = v;
    }
    // stage w_in (identity copy, [o][c] row-major) into wt_lds
    #pragma unroll
    for (int i = 0; i < 2; ++i)
        ((floatx4*)wt_lds)[tid + 512 * i] = ((const floatx4*)w_in)[tid + 512 * i];
    // stage hin tile (64 ch x 16 px) into stile (aliased)
    if (tid < 256) {
        int cc = tid >> 2, f4 = tid & 3;
        ((floatx4*)stile)[tid] = *(const floatx4*)&hin[(b * 64 + cc) * HW + p0 + f4 * 4];
    }
    __syncthreads();

    // ---- conv_in (per wave, own group): x[g][t][px] = sum_c w_in[g8+t][c]*hin[c][px] + b_in
    {
        floatx2 xacc; xacc.x = b_in[g * 8 + q]; xacc.y = b_in[g * 8 + q + 4];
        #pragma unroll 8
        for (int cc = 0; cc < 64; ++cc) {
            float hv = stile[cc * 16 + s];
            floatx2 w;
            w.x = wt_lds[(g * 8 + q) * 64 + cc];
            w.y = wt_lds[(g * 8 + q + 4) * 64 + cc];
            floatx2 h2; h2.x = hv; h2.y = hv;
            xacc = xacc + w * h2;
        }
        x_lds[g * 128 + q * 16 + s]       = xacc.x;
        x_lds[g * 128 + (q + 4) * 16 + s] = xacc.y;
    }
    // zero h state (4608 u32)
    #pragma unroll
    for (int i = 0; i < 9; ++i)
        ((unsigned*)h_lds)[tid + 512 * i] = 0u;
    __syncthreads();   // hin/w_in reads + x/h writes complete

    // stage w_out ([o][c], as-is) into wt_lds for the epilogue
    #pragma unroll
    for (int i = 0; i < 2; ++i)
        ((floatx4*)wt_lds)[tid + 512 * i] = ((const floatx4*)w_out)[tid + 512 * i];

    _Float16* hrow = h_lds + wv * 16 * 72;
    float bs = b_s_p[0];

    // c-state, stored PRE-SCALED by 2*log2(e)
    float c_st[4][4];
    #pragma unroll
    for (int hb = 0; hb < 4; ++hb)
        #pragma unroll
        for (int r = 0; r < 4; ++r) c_st[hb][r] = 0.0f;

    for (int t = 0; t < TT; ++t) {
        // Memory barrier: forbids caching LDS (frags/wxb/x/h) in registers
        // across iterations (r7/r12: caching balloons regs past the
        // occupancy cliff; LDS re-reads are cheaper than lost occupancy).
        asm volatile("" ::: "memory");

        halfx8 a0 = *(const halfx8*)(hrow + s * 72 + q * 8);        // k = 0..31
        halfx8 a1 = *(const halfx8*)(hrow + s * 72 + q * 8 + 32);   // k = 32..63

        // s_{t-1} = h_t @ w_s via MFMA (col 0 only); lanes s==0 hold seq q*4+r
        if (t > 0) {
            halfx8 sb0 = *(const halfx8*)&wfrag_lds[32 * 64 + lane];
            halfx8 sb1 = *(const halfx8*)&wfrag_lds[33 * 64 + lane];
            floatx4 sa = {0.f, 0.f, 0.f, 0.f};
            sa = __builtin_amdgcn_mfma_f32_16x16x32_f16(a0, sb0, sa, 0, 0, 0);
            sa = __builtin_amdgcn_mfma_f32_16x16x32_f16(a1, sb1, sa, 0, 0, 0);
            if (s == 0) {
                floatx4 o4 = {sa[0] + bs, sa[1] + bs, sa[2] + bs, sa[3] + bs};
                *(floatx4*)&stile[(g * 8 + (t - 1)) * 16 + q * 4] = o4;
            }
        }

        floatx4 xv = *(const floatx4*)&x_lds[g * 128 + t * 16 + q * 4];
        floatx2 xlo; xlo.x = xv[0]; xlo.y = xv[1];
        floatx2 xhi; xhi.x = xv[2]; xhi.y = xv[3];

        halfx4 hpack[4];   // per-row packed h (hb-contiguous thanks to r11 perm)

        #pragma unroll
        for (int hb = 0; hb < 4; ++hb) {
            floatx4 acc[4];
            #pragma unroll
            for (int gi = 0; gi < 4; ++gi) {
                int nb = hb + 4 * gi;
                floatx2 wb = wxb_lds[s + 16 * nb];
                floatx2 lo = xlo * wb.x + wb.y;     // x*w_x + bias as C init (pk_fma)
                floatx2 hi = xhi * wb.x + wb.y;
                floatx4 a = {lo.x, lo.y, hi.x, hi.y};
                halfx8 b0 = *(const halfx8*)&wfrag_lds[(nb * 2 + 0) * 64 + lane];
                halfx8 b1 = *(const halfx8*)&wfrag_lds[(nb * 2 + 1) * 64 + lane];
                a = __builtin_amdgcn_mfma_f32_16x16x32_f16(a0, b0, a, 0, 0, 0);
                a = __builtin_amdgcn_mfma_f32_16x16x32_f16(a1, b1, a, 0, 0, 0);
                acc[gi] = a;
            }
            #pragma unroll
            for (int p = 0; p < 2; ++p) {
                int r0 = 2 * p;
                // accs are pre-scaled: Ei=e^-i, Ef=e^-f, Eo=e^-o, Eg=e^{2g}
                floatx2 Ei; Ei.x = fast_exp2(acc[0][r0]); Ei.y = fast_exp2(acc[0][r0 + 1]);
                floatx2 Ef; Ef.x = fast_exp2(acc[1][r0]); Ef.y = fast_exp2(acc[1][r0 + 1]);
                floatx2 Eg; Eg.x = fast_exp2(acc[2][r0]); Eg.y = fast_exp2(acc[2][r0 + 1]);
                floatx2 Eo; Eo.x = fast_exp2(acc[3][r0]); Eo.y = fast_exp2(acc[3][r0 + 1]);
                floatx2 Bf  = Ef + 1.0f;
                floatx2 Pig = (Ei + 1.0f) * (Eg + 1.0f);
                floatx2 cp; cp.x = c_st[hb][r0]; cp.y = c_st[hb][r0 + 1];
                // cs' = f*cs + 2log2e * i*g  ==  [cs*Pig + SG*(Eg-1)*Bf] / (Bf*Pig)
                floatx2 num = cp * Pig + (Eg * SG - SG) * Bf;   // fma: SG*(Eg-1) exact
                floatx2 cs  = num * rcpx2(Bf * Pig);
                c_st[hb][r0] = cs.x; c_st[hb][r0 + 1] = cs.y;
                // h = o*tanh(c) = (Ec-1) / ((1+Eo)(1+Ec)),  Ec = exp2(cs) = e^{2c}
                floatx2 Ec  = exp2x2(cs);
                floatx2 hn  = (Ec - 1.0f) * rcpx2((Eo + 1.0f) * (Ec + 1.0f));
                hpack[r0 + 0][hb] = (_Float16)hn.x;
                hpack[r0 + 1][hb] = (_Float16)hn.y;
            }
        }
        // state for t+1: 4x ds_write_b64, hid = 4s..4s+3 per row (r11 perm)
        {
            _Float16* wp = hrow + (q * 4) * 72 + 4 * s;
            *(halfx4*)(wp +   0) = hpack[0];
            *(halfx4*)(wp +  72) = hpack[1];
            *(halfx4*)(wp + 144) = hpack[2];
            *(halfx4*)(wp + 216) = hpack[3];
        }
    }
    // final s_7 from h_8
    {
        asm volatile("" ::: "memory");
        halfx8 a0 = *(const halfx8*)(hrow + s * 72 + q * 8);
        halfx8 a1 = *(const halfx8*)(hrow + s * 72 + q * 8 + 32);
        halfx8 sb0 = *(const halfx8*)&wfrag_lds[32 * 64 + lane];
        halfx8 sb1 = *(const halfx8*)&wfrag_lds[33 * 64 + lane];
        floatx4 sa = {0.f, 0.f, 0.f, 0.f};
        sa = __builtin_amdgcn_mfma_f32_16x16x32_f16(a0, sb0, sa, 0, 0, 0);
        sa = __builtin_amdgcn_mfma_f32_16x16x32_f16(a1, sb1, sa, 0, 0, 0);
        if (s == 0) {
            floatx4 o4 = {sa[0] + bs, sa[1] + bs, sa[2] + bs, sa[3] + bs};
            *(floatx4*)&stile[(g * 8 + 7) * 16 + q * 4] = o4;
        }
    }
    __syncthreads();   // stile (all 64 channels) + wt_lds (w_out) ready

    // ---- conv_out epilogue: out[b][o][p0+px] = sum_c w_out[o][c]*stile[c][px] + b_out[o]
    {
        int px = tid & 15;
        int oo = tid >> 4;                 // 0..31 -> outputs oo and oo+32
        floatx2 acc; acc.x = b_out[oo]; acc.y = b_out[oo + 32];
        #pragma unroll
        for (int c4 = 0; c4 < 16; ++c4) {
            floatx4 w0 = *(const floatx4*)&wt_lds[oo * 64 + c4 * 4];
            floatx4 w1 = *(const floatx4*)&wt_lds[(oo + 32) * 64 + c4 * 4];
            #pragma unroll
            for (int j = 0; j < 4; ++j) {
                float sv = stile[(c4 * 4 + j) * 16 + px];
                acc.x += w0[j] * sv;
                acc.y += w1[j] * sv;
            }
        }
        out[(b * 64 + oo) * HW + p0 + px]      = acc.x;
        out[(b * 64 + oo + 32) * HW + p0 + px] = acc.y;
    }
}

extern "C" void kernel_launch(void* const* d_in, const int* in_sizes, int n_in,
                              void* d_out, int out_size, void* d_ws, size_t ws_size,
                              hipStream_t stream) {
    const float* h     = (const float*)d_in[0];
    const float* w_in  = (const float*)d_in[1];
    const float* b_in  = (const float*)d_in[2];
    const float* w_ih  = (const float*)d_in[3];
    const float* w_hh  = (const float*)d_in[4];
    const float* b_ih  = (const float*)d_in[5];
    const float* b_hh  = (const float*)d_in[6];
    const float* w_s   = (const float*)d_in[7];
    const float* b_s   = (const float*)d_in[8];
    const float* w_out = (const float*)d_in[9];
    const float* b_out = (const float*)d_in[10];
    float* out = (float*)d_out;

    // single launch: repack + conv_in + LSTM + conv_out all in one kernel
    // (r14: the separate prep dispatch + launch gap was ~46 us of the bench).
    lstm_kernel<<<2048, 512, 0, stream>>>(h, out, w_in, b_in, w_ih, w_hh,
                                          b_ih, b_hh, w_s, b_s, b_out, w_out);
}

// Round 8
// 226.266 us; speedup vs baseline: 1.0103x; 1.0103x over previous
//
#include <hip/hip_runtime.h>
#include <hip/hip_bf16.h>

// ---------------- problem constants ----------------
#define HW    4096      // H*W
#define BB    8         // batch
#define TT    8         // time steps

// ws layout (in floats)
constexpr int OFF_WFRAG = 0;                   // 34 frags * 64 lanes * 16B = 8704 floats
constexpr int OFF_WXB   = 12800;               // 256 float2 = 512 floats {w_x, bias}

// gate pre-scales folded into w_hh / w_x / bias at prep time:
//   i,f,o rows: * -log2(e)   -> sigmoid(x) = rcp(exp2(acc)+1)
//   g rows:     * 2*log2(e)  -> tanh(x) = (exp2(acc)-1)/(exp2(acc)+1)
constexpr float SI = -1.44269504088896340736f; // -log2(e)
constexpr float SG =  2.88539008177792681472f; // 2*log2(e)

typedef _Float16 halfx8 __attribute__((ext_vector_type(8)));
typedef _Float16 halfx4 __attribute__((ext_vector_type(4)));
typedef float    floatx4 __attribute__((ext_vector_type(4)));
typedef float    floatx2 __attribute__((ext_vector_type(2)));

__device__ inline float fast_exp2(float x) {
#if __has_builtin(__builtin_amdgcn_exp2f)
    return __builtin_amdgcn_exp2f(x);
#else
    return __builtin_exp2f(x);
#endif
}
__device__ inline float fast_rcp(float x) {
#if __has_builtin(__builtin_amdgcn_rcpf)
    return __builtin_amdgcn_rcpf(x);
#else
    return 1.0f / x;
#endif
}
__device__ inline floatx2 exp2x2(floatx2 x) {
    floatx2 r; r.x = fast_exp2(x.x); r.y = fast_exp2(x.y); return r;
}
// r16: PAIRWISE-BATCHED reciprocal — 1 v_rcp + 3 v_mul instead of 2 v_rcp.
// All call sites pass denominators in [1, ~4e3] (products <= ~1.6e7), so
// rcp(x*y) cannot overflow/underflow. r15 POST-MORTEM: the 4-way cross-row
// batch produced NaN (mechanism unidentified despite verified algebra+range);
// this is the minimal form of the same trans-amortization, confined to the
// proven rcpx2 interface. If THIS NaNs, batching is indicted -> revert r13.
__device__ inline floatx2 rcpx2(floatx2 x) {
    float R = fast_rcp(x.x * x.y);
    floatx2 r; r.x = R * x.y; r.y = R * x.x; return r;
}

union pack8 { _Float16 h[8]; uint4 u; };

// ---------------- prep: repack weights into d_ws (10 blocks) ----------------
// r9: folds activation pre-scales (SI/SG) into the f16 B-fragments and the
// {w_x,bias} table so t-loop exp2 args come straight out of the MFMA accs.
// r11: gate-column PERMUTATION — frag column sc of block nb=(hb+4gi) holds
// orig gate row 64*gi + 4*sc + hb. Thread (s,hb) then produces hid = 4s+hb
// -> its 4 hb-values are CONTIGUOUS in h_lds -> one ds_write_b64 per row.
// r14: keep split prep (the ~45us bench-vs-dispatch gap is fixed harness
// overhead, not this launch; folding it in cost +7us on the lstm dispatch).
__global__ __launch_bounds__(256) void prep_kernel(
    const float* __restrict__ w_ih,  const float* __restrict__ w_hh,
    const float* __restrict__ b_ih,  const float* __restrict__ b_hh,
    const float* __restrict__ w_s,   const float* __restrict__ w_out,
    float* __restrict__ ws_f) {
    int tid = threadIdx.x;
    int bid = blockIdx.x;
    if (bid < 9) {
        int e = bid * 256 + tid;
        uint4* wf = (uint4*)(ws_f + OFF_WFRAG);
        if (e < 2048) {
            int l  = e & 63;
            int fi = e >> 6;
            int nb = fi >> 1, kc = fi & 1;
            int hb = nb & 3, gi = nb >> 2;
            int gate = gi * 64 + 4 * (l & 15) + hb;   // r11 permuted column
            int hid  = kc * 32 + (l >> 4) * 8;
            float sc = (gi == 2) ? SG : SI;
            const float* src = w_hh + gate * 64 + hid;
            pack8 p;
            #pragma unroll
            for (int j = 0; j < 8; ++j) p.h[j] = (_Float16)(src[j] * sc);
            wf[e] = p.u;
        } else if (e < 2176) {
            // s-projection fragments (frags 32,33): B[k][0]=w_s[k] (UNSCALED)
            int t2 = e - 2048;
            int l = t2 & 63, kc = t2 >> 6;
            pack8 p;
            #pragma unroll
            for (int j = 0; j < 8; ++j) p.h[j] = (_Float16)0.0f;
            if ((l & 15) == 0) {
                #pragma unroll
                for (int j = 0; j < 8; ++j)
                    p.h[j] = (_Float16)w_s[kc * 32 + (l >> 4) * 8 + j];
            }
            wf[e] = p.u;
        }
    } else {
        // {w_x, bias} pairs, permuted + pre-scaled.
        // read idx = s + 16*hb + 64*gi  ->  gate 64*gi + 4*s + hb
        int s_ = tid & 15, hb = (tid >> 4) & 3, gi = tid >> 6;
        int gate = gi * 64 + 4 * s_ + hb;
        float sc = (gi == 2) ? SG : SI;
        floatx2 v; v.x = w_ih[gate] * sc; v.y = (b_ih[gate] + b_hh[gate]) * sc;
        ((floatx2*)(ws_f + OFF_WXB))[tid] = v;
    }
}

// ---------------- fully fused conv_in + LSTM + conv_out ----------------
// Block = 512 threads = 8 waves = ONE 16-pixel tile x ALL 8 groups.
// r9:  common-denominator LSTM cell (weights pre-scaled): 5 exp2 + 2 rcp/elem.
// r16: pairwise-batched rcpx2 -> 5 exp2 + 1 rcp/elem (trans issue -14%).
// r12/r13: occupancy cliff for this 8-wave block is between reported-VGPR
//      64 (2 blocks/CU, occ ~42%) and 108 (1 block/CU, occ 22%). Keep
//      reported VGPR <= 64; weight frags/wxb stay in LDS per-t (asm clobber).
// LDS = 79872 B <= 81920 -> 2 blocks/CU = 16 waves/CU.
__global__ __launch_bounds__(512) void lstm_kernel(
    const float* __restrict__ hin,    // (B, 64, HW) original input h
    const float* __restrict__ ws_f,   // tables
    float* __restrict__ out,          // (B, 64, HW) final output
    const float* __restrict__ w_in,   // (64, 64)
    const float* __restrict__ b_in,   // (64,)
    const float* __restrict__ b_s_p,  // (1,)
    const float* __restrict__ b_out,  // (64,)
    const float* __restrict__ w_out) {// (64, 64) [o][c]
    __shared__ uint4 wfrag_lds[2176];                  // 34816 B
    __shared__ floatx2 wxb_lds[256];                   // 2048 B
    __shared__ __align__(16) float x_lds[1024];        // 4096 B: [g][t][px16]
    __shared__ __align__(16) _Float16 h_lds[9216];     // 18432 B: 8 waves x 16 x 72
    __shared__ __align__(16) float stile[1024];        // 4096 B: [c64][px16]; aliases hin staging
    __shared__ __align__(16) float wt_lds[4096];       // 16384 B: w_in, then w_out

    int tid = threadIdx.x;
    int ptile = blockIdx.x & 255;         // 256 tiles of 16 px
    int b     = blockIdx.x >> 8;
    int p0 = ptile * 16;

    int lane = tid & 63;
    int wv   = tid >> 6;                  // 0..7 == group g
    int g    = wv;
    int s    = lane & 15;                 // seq-local == pixel-local
    int q    = lane >> 4;

    // stage weight fragments (shared by all 8 waves)
    const uint4* wfg = (const uint4*)(ws_f + OFF_WFRAG);
    #pragma unroll
    for (int i = 0; i < 5; ++i) {
        int e = tid + 512 * i;
        if (e < 2176) wfrag_lds[e] = wfg[e];
    }
    if (tid < 256) wxb_lds[tid] = ((const floatx2*)(ws_f + OFF_WXB))[tid];
    // stage w_in (identity copy, [o][c] row-major) into wt_lds
    #pragma unroll
    for (int i = 0; i < 2; ++i)
        ((floatx4*)wt_lds)[tid + 512 * i] = ((const floatx4*)w_in)[tid + 512 * i];
    // stage hin tile (64 ch x 16 px) into stile (aliased)
    if (tid < 256) {
        int cc = tid >> 2, f4 = tid & 3;
        ((floatx4*)stile)[tid] = *(const floatx4*)&hin[(b * 64 + cc) * HW + p0 + f4 * 4];
    }
    __syncthreads();

    // ---- conv_in (per wave, own group): x[g][t][px] = sum_c w_in[g8+t][c]*hin[c][px] + b_in
    {
        floatx2 xacc; xacc.x = b_in[g * 8 + q]; xacc.y = b_in[g * 8 + q + 4];
        #pragma unroll 8
        for (int cc = 0; cc < 64; ++cc) {
            float hv = stile[cc * 16 + s];
            floatx2 w;
            w.x = wt_lds[(g * 8 + q) * 64 + cc];
            w.y = wt_lds[(g * 8 + q + 4) * 64 + cc];
            floatx2 h2; h2.x = hv; h2.y = hv;
            xacc = xacc + w * h2;
        }
        x_lds[g * 128 + q * 16 + s]       = xacc.x;
        x_lds[g * 128 + (q + 4) * 16 + s] = xacc.y;
    }
    // zero h state (4608 u32)
    #pragma unroll
    for (int i = 0; i < 9; ++i)
        ((unsigned*)h_lds)[tid + 512 * i] = 0u;
    __syncthreads();   // hin/w_in reads + x/h writes complete

    // stage w_out ([o][c], as-is) into wt_lds for the epilogue
    #pragma unroll
    for (int i = 0; i < 2; ++i)
        ((floatx4*)wt_lds)[tid + 512 * i] = ((const floatx4*)w_out)[tid + 512 * i];

    _Float16* hrow = h_lds + wv * 16 * 72;
    float bs = b_s_p[0];

    // c-state, stored PRE-SCALED by 2*log2(e)
    float c_st[4][4];
    #pragma unroll
    for (int hb = 0; hb < 4; ++hb)
        #pragma unroll
        for (int r = 0; r < 4; ++r) c_st[hb][r] = 0.0f;

    for (int t = 0; t < TT; ++t) {
        // Memory barrier: forbids caching LDS (frags/wxb/x/h) in registers
        // across iterations (r7/r12: caching balloons regs past the
        // occupancy cliff; LDS re-reads are cheaper than lost occupancy).
        asm volatile("" ::: "memory");

        halfx8 a0 = *(const halfx8*)(hrow + s * 72 + q * 8);        // k = 0..31
        halfx8 a1 = *(const halfx8*)(hrow + s * 72 + q * 8 + 32);   // k = 32..63

        // s_{t-1} = h_t @ w_s via MFMA (col 0 only); lanes s==0 hold seq q*4+r
        if (t > 0) {
            halfx8 sb0 = *(const halfx8*)&wfrag_lds[32 * 64 + lane];
            halfx8 sb1 = *(const halfx8*)&wfrag_lds[33 * 64 + lane];
            floatx4 sa = {0.f, 0.f, 0.f, 0.f};
            sa = __builtin_amdgcn_mfma_f32_16x16x32_f16(a0, sb0, sa, 0, 0, 0);
            sa = __builtin_amdgcn_mfma_f32_16x16x32_f16(a1, sb1, sa, 0, 0, 0);
            if (s == 0) {
                floatx4 o4 = {sa[0] + bs, sa[1] + bs, sa[2] + bs, sa[3] + bs};
                *(floatx4*)&stile[(g * 8 + (t - 1)) * 16 + q * 4] = o4;
            }
        }

        floatx4 xv = *(const floatx4*)&x_lds[g * 128 + t * 16 + q * 4];
        floatx2 xlo; xlo.x = xv[0]; xlo.y = xv[1];
        floatx2 xhi; xhi.x = xv[2]; xhi.y = xv[3];

        halfx4 hpack[4];   // per-row packed h (hb-contiguous thanks to r11 perm)

        #pragma unroll
        for (int hb = 0; hb < 4; ++hb) {
            floatx4 acc[4];
            #pragma unroll
            for (int gi = 0; gi < 4; ++gi) {
                int nb = hb + 4 * gi;
                floatx2 wb = wxb_lds[s + 16 * nb];
                floatx2 lo = xlo * wb.x + wb.y;     // x*w_x + bias as C init (pk_fma)
                floatx2 hi = xhi * wb.x + wb.y;
                floatx4 a = {lo.x, lo.y, hi.x, hi.y};
                halfx8 b0 = *(const halfx8*)&wfrag_lds[(nb * 2 + 0) * 64 + lane];
                halfx8 b1 = *(const halfx8*)&wfrag_lds[(nb * 2 + 1) * 64 + lane];
                a = __builtin_amdgcn_mfma_f32_16x16x32_f16(a0, b0, a, 0, 0, 0);
                a = __builtin_amdgcn_mfma_f32_16x16x32_f16(a1, b1, a, 0, 0, 0);
                acc[gi] = a;
            }
            #pragma unroll
            for (int p = 0; p < 2; ++p) {
                int r0 = 2 * p;
                // accs are pre-scaled: Ei=e^-i, Ef=e^-f, Eo=e^-o, Eg=e^{2g}
                floatx2 Ei; Ei.x = fast_exp2(acc[0][r0]); Ei.y = fast_exp2(acc[0][r0 + 1]);
                floatx2 Ef; Ef.x = fast_exp2(acc[1][r0]); Ef.y = fast_exp2(acc[1][r0 + 1]);
                floatx2 Eg; Eg.x = fast_exp2(acc[2][r0]); Eg.y = fast_exp2(acc[2][r0 + 1]);
                floatx2 Eo; Eo.x = fast_exp2(acc[3][r0]); Eo.y = fast_exp2(acc[3][r0 + 1]);
                floatx2 Bf  = Ef + 1.0f;
                floatx2 Pig = (Ei + 1.0f) * (Eg + 1.0f);
                floatx2 cp; cp.x = c_st[hb][r0]; cp.y = c_st[hb][r0 + 1];
                // cs' = f*cs + 2log2e * i*g  ==  [cs*Pig + SG*(Eg-1)*Bf] / (Bf*Pig)
                floatx2 num = cp * Pig + (Eg * SG - SG) * Bf;   // fma: SG*(Eg-1) exact
                floatx2 cs  = num * rcpx2(Bf * Pig);
                c_st[hb][r0] = cs.x; c_st[hb][r0 + 1] = cs.y;
                // h = o*tanh(c) = (Ec-1) / ((1+Eo)(1+Ec)),  Ec = exp2(cs) = e^{2c}
                floatx2 Ec  = exp2x2(cs);
                floatx2 hn  = (Ec - 1.0f) * rcpx2((Eo + 1.0f) * (Ec + 1.0f));
                hpack[r0 + 0][hb] = (_Float16)hn.x;
                hpack[r0 + 1][hb] = (_Float16)hn.y;
            }
        }
        // state for t+1: 4x ds_write_b64, hid = 4s..4s+3 per row (r11 perm)
        {
            _Float16* wp = hrow + (q * 4) * 72 + 4 * s;
            *(halfx4*)(wp +   0) = hpack[0];
            *(halfx4*)(wp +  72) = hpack[1];
            *(halfx4*)(wp + 144) = hpack[2];
            *(halfx4*)(wp + 216) = hpack[3];
        }
    }
    // final s_7 from h_8
    {
        asm volatile("" ::: "memory");
        halfx8 a0 = *(const halfx8*)(hrow + s * 72 + q * 8);
        halfx8 a1 = *(const halfx8*)(hrow + s * 72 + q * 8 + 32);
        halfx8 sb0 = *(const halfx8*)&wfrag_lds[32 * 64 + lane];
        halfx8 sb1 = *(const halfx8*)&wfrag_lds[33 * 64 + lane];
        floatx4 sa = {0.f, 0.f, 0.f, 0.f};
        sa = __builtin_amdgcn_mfma_f32_16x16x32_f16(a0, sb0, sa, 0, 0, 0);
        sa = __builtin_amdgcn_mfma_f32_16x16x32_f16(a1, sb1, sa, 0, 0, 0);
        if (s == 0) {
            floatx4 o4 = {sa[0] + bs, sa[1] + bs, sa[2] + bs, sa[3] + bs};
            *(floatx4*)&stile[(g * 8 + 7) * 16 + q * 4] = o4;
        }
    }
    __syncthreads();   // stile (all 64 channels) + wt_lds (w_out) ready

    // ---- conv_out epilogue: out[b][o][p0+px] = sum_c w_out[o][c]*stile[c][px] + b_out[o]
    {
        int px = tid & 15;
        int oo = tid >> 4;                 // 0..31 -> outputs oo and oo+32
        floatx2 acc; acc.x = b_out[oo]; acc.y = b_out[oo + 32];
        #pragma unroll
        for (int c4 = 0; c4 < 16; ++c4) {
            floatx4 w0 = *(const floatx4*)&wt_lds[oo * 64 + c4 * 4];
            floatx4 w1 = *(const floatx4*)&wt_lds[(oo + 32) * 64 + c4 * 4];
            #pragma unroll
            for (int j = 0; j < 4; ++j) {
                float sv = stile[(c4 * 4 + j) * 16 + px];
                acc.x += w0[j] * sv;
                acc.y += w1[j] * sv;
            }
        }
        out[(b * 64 + oo) * HW + p0 + px]      = acc.x;
        out[(b * 64 + oo + 32) * HW + p0 + px] = acc.y;
    }
}

extern "C" void kernel_launch(void* const* d_in, const int* in_sizes, int n_in,
                              void* d_out, int out_size, void* d_ws, size_t ws_size,
                              hipStream_t stream) {
    const float* h     = (const float*)d_in[0];
    const float* w_in  = (const float*)d_in[1];
    const float* b_in  = (const float*)d_in[2];
    const float* w_ih  = (const float*)d_in[3];
    const float* w_hh  = (const float*)d_in[4];
    const float* b_ih  = (const float*)d_in[5];
    const float* b_hh  = (const float*)d_in[6];
    const float* w_s   = (const float*)d_in[7];
    const float* b_s   = (const float*)d_in[8];
    const float* w_out = (const float*)d_in[9];
    const float* b_out = (const float*)d_in[10];
    float* out = (float*)d_out;
    float* ws  = (float*)d_ws;

    prep_kernel<<<10, 256, 0, stream>>>(w_ih, w_hh, b_ih, b_hh, w_s, w_out, ws);
    // fully fused conv_in + LSTM + conv_out: hin -> out. 2048 blocks x 512 threads.
    lstm_kernel<<<2048, 512, 0, stream>>>(h, ws, out, w_in, b_in, b_s, b_out, w_out);
}